// Round 5
// baseline (316.430 us; speedup 1.0000x reference)
//
#include <hip/hip_runtime.h>
#include <math.h>

#define B_  8
#define T_  2048
#define S_  2048
#define D_  512

typedef _Float16 half8   __attribute__((ext_vector_type(8)));
typedef _Float16 half4_t __attribute__((ext_vector_type(4)));
typedef float    floatx4 __attribute__((ext_vector_type(4)));

__device__ __forceinline__ floatx4 mfma16(half8 a, half8 b, floatx4 c) {
  return __builtin_amdgcn_mfma_f32_16x16x32_f16(a, b, c, 0, 0, 0);
}

// async global->LDS, 16B per lane; lds base wave-uniform (HW adds lane*16)
__device__ __forceinline__ void async16(void* lds, const void* g) {
  __builtin_amdgcn_global_load_lds(
      (const __attribute__((address_space(1))) void*)g,
      (__attribute__((address_space(3))) void*)lds, 16, 0, 0);
}

// ---------------------------------------------------------------------------
// Kernel 1: Vt[b][d][s] = (fp16) attn[b][s][d]  AND  X16 = (fp16) attn (row-major)
// ---------------------------------------------------------------------------
__global__ __launch_bounds__(256) void transpose_cast_kernel(
    const float* __restrict__ attn, _Float16* __restrict__ Vt,
    _Float16* __restrict__ X16) {
  __shared__ _Float16 tile[32][33];
  const int tx = threadIdx.x, ty = threadIdx.y;
  const int b = blockIdx.z, s0 = blockIdx.y * 32, d0 = blockIdx.x * 32;
  const float* src = attn + ((size_t)b * S_ + s0) * D_ + d0;
#pragma unroll
  for (int i = 0; i < 4; ++i) {
    int s = ty + i * 8;
    _Float16 h = (_Float16)src[(size_t)s * D_ + tx];
    tile[tx][s] = h;
    X16[((size_t)b * S_ + s0 + s) * D_ + d0 + tx] = h;
  }
  __syncthreads();
  _Float16* dst = Vt + ((size_t)b * D_ + d0) * S_ + s0;
#pragma unroll
  for (int i = 0; i < 4; ++i) {
    int d = ty + i * 8;
    dst[(size_t)d * S_ + tx] = tile[d][tx];
  }
}

// ---------------------------------------------------------------------------
// Kernel 1b: W16 = (fp16) W_f   (512x512)
// ---------------------------------------------------------------------------
__global__ __launch_bounds__(256) void wcast_kernel(
    const float* __restrict__ W, _Float16* __restrict__ W16) {
  int idx = (blockIdx.x * 256 + threadIdx.x) * 4;
  floatx4 v = *(const floatx4*)&W[idx];
  half4_t h;
#pragma unroll
  for (int j = 0; j < 4; ++j) h[j] = (_Float16)v[j];
  *(half4_t*)&W16[idx] = h;
}

// ---------------------------------------------------------------------------
// Kernel 2: K16 = X16 @ W16^T + bias   (m97-style: global_load_lds, dbuf BK=32)
//   256 thr / 4 waves, tile 128x128, wave 64x64. Grid (128,4) = 512 blocks.
// ---------------------------------------------------------------------------
__global__ __launch_bounds__(256, 2) void keys_gemm_kernel(
    const _Float16* __restrict__ X16, const _Float16* __restrict__ W16,
    const float* __restrict__ bias, _Float16* __restrict__ K16) {
  __shared__ _Float16 As[2][128 * 32];
  __shared__ _Float16 Bs[2][128 * 32];
  const int t = threadIdx.x;
  const int w = t >> 6, lane = t & 63, qd = lane >> 4, n = lane & 15;
  const int wm = w >> 1, wn = w & 1;
  const int m0 = blockIdx.x * 128, n0 = blockIdx.y * 128;

  floatx4 acc[4][4];
#pragma unroll
  for (int i = 0; i < 4; ++i)
#pragma unroll
    for (int j = 0; j < 4; ++j) {
      floatx4 z = {0.f, 0.f, 0.f, 0.f};
      acc[i][j] = z;
    }

  const int srow = (lane >> 2);          // 0..15 within 16-row group
  const int schunk = (lane & 3) * 8;     // halfs offset within 32-half row

  // stage k-step ks into buffer buf
  auto stage = [&](int buf, int k0) {
#pragma unroll
    for (int i = 0; i < 2; ++i) {
      int row = w * 32 + i * 16;         // A rows row..row+16
      async16(&As[buf][row * 32],
              X16 + (size_t)(m0 + row + srow) * D_ + k0 + schunk);
      async16(&Bs[buf][row * 32],
              W16 + (size_t)(n0 + row + srow) * D_ + k0 + schunk);
    }
  };

  stage(0, 0);
  __syncthreads();

  for (int ks = 0; ks < 16; ++ks) {
    const int cur = ks & 1;
    if (ks < 15) stage(cur ^ 1, (ks + 1) * 32);

    half8 a[4], bb[4];
#pragma unroll
    for (int mt = 0; mt < 4; ++mt)
      a[mt] = *(const half8*)&As[cur][(wm * 64 + mt * 16 + n) * 32 + qd * 8];
#pragma unroll
    for (int nt = 0; nt < 4; ++nt)
      bb[nt] = *(const half8*)&Bs[cur][(wn * 64 + nt * 16 + n) * 32 + qd * 8];
#pragma unroll
    for (int mt = 0; mt < 4; ++mt)
#pragma unroll
      for (int nt = 0; nt < 4; ++nt)
        acc[mt][nt] = mfma16(a[mt], bb[nt], acc[mt][nt]);

    __syncthreads();   // drains prefetch + WAR for cur buffer reuse
  }

#pragma unroll
  for (int nt = 0; nt < 4; ++nt) {
    int col = n0 + wn * 64 + nt * 16 + n;
    float bv = bias[col];
#pragma unroll
    for (int mt = 0; mt < 4; ++mt)
#pragma unroll
      for (int r = 0; r < 4; ++r) {
        int row = m0 + wm * 64 + mt * 16 + qd * 4 + r;
        K16[(size_t)row * D_ + col] = (_Float16)(acc[mt][nt][r] + bv);
      }
  }
}

// ---------------------------------------------------------------------------
// Kernel 3: flash attention — paired waves: duplicate QK, split PV d-halves.
//   512 thr / 8 waves, BM=64, BN=32, grid 256 (1 block/CU, 2 waves/SIMD).
//   Wave (rg = w&3, dh = w>>2): QK + softmax for rows rg*16 (wave-local,
//   duplicated across dh siblings -> zero cross-wave traffic), PV for
//   d in [dh*256, dh*256+256). 1 barrier per s-tile. K/V dbuf via async16.
//   l accumulated by MFMA against ones fragment.
// ---------------------------------------------------------------------------
__global__ __launch_bounds__(512, 2) void flash_kernel(
    const float* __restrict__ Qf, const _Float16* __restrict__ K16,
    const _Float16* __restrict__ Vt, float* __restrict__ out) {
  __shared__ _Float16 Klds[2][32][512];  // K-chunk slot l holds src chunk l^(s&7)
  __shared__ _Float16 Vlds[2][512][32];  // row d: V[d][s0..s0+32]
  __shared__ _Float16 Pscr[8][16][40];   // per-wave private P transpose scratch

  const int t = threadIdx.x;
  const int w = t >> 6, lane = t & 63, qd = lane >> 4, n = lane & 15;
  const int rg = w & 3, dh = w >> 2;
  const int bid = blockIdx.x;
  const int b = bid & 7, t0 = (bid >> 3) * 64;

  const _Float16* Kb = K16 + (size_t)b * S_ * D_;
  const _Float16* Vb = Vt + (size_t)b * D_ * S_;

  // ---- Q -> registers (wave's 16 rows = t0 + rg*16 + n) ----
  half8 qreg[16];
  {
    const float* qrow = Qf + ((size_t)b * T_ + t0 + rg * 16 + n) * D_;
#pragma unroll
    for (int kk = 0; kk < 16; ++kk) {
      floatx4 v0 = *(const floatx4*)&qrow[kk * 32 + qd * 8];
      floatx4 v1 = *(const floatx4*)&qrow[kk * 32 + qd * 8 + 4];
      half8 h;
#pragma unroll
      for (int j = 0; j < 4; ++j) { h[j] = (_Float16)v0[j]; h[j + 4] = (_Float16)v1[j]; }
      qreg[kk] = h;
    }
  }

  floatx4 O[17];   // [0..15] d-tiles of wave's 256-col half, [16] = l
#pragma unroll
  for (int ng = 0; ng < 17; ++ng) {
    floatx4 z = {0.f, 0.f, 0.f, 0.f};
    O[ng] = z;
  }
  float m_st[4];
#pragma unroll
  for (int r = 0; r < 4; ++r) m_st[r] = -1e30f;

  half8 ones8;
#pragma unroll
  for (int j = 0; j < 8; ++j) ones8[j] = (_Float16)1.0f;

  // staging helpers: 8 waves cover K (32 rows x 1KB) and V (512 rows x 64B)
  auto stageK = [&](int buf, int s0) {
#pragma unroll
    for (int i = 0; i < 4; ++i) {
      int srow = w * 4 + i;
      async16(&Klds[buf][srow][0],
              Kb + (size_t)(s0 + srow) * D_ + ((lane ^ (srow & 7)) * 8));
    }
  };
  auto stageV = [&](int buf, int s0) {
#pragma unroll
    for (int i = 0; i < 4; ++i) {
      int d0 = (w * 4 + i) * 16;
      async16(&Vlds[buf][d0][0],
              Vb + (size_t)(d0 + (lane >> 2)) * S_ + s0 + (lane & 3) * 8);
    }
  };

  stageK(0, 0);
  stageV(0, 0);
  __syncthreads();

  const int n7 = n & 7;

  for (int st = 0; st < S_ / 32; ++st) {
    const int cur = st & 1;
    const int s0 = st * 32;

    // prefetch next tile into other buffer (in flight across whole tile)
    if (st < S_ / 32 - 1) {
      stageK(cur ^ 1, s0 + 32);
      stageV(cur ^ 1, s0 + 32);
    }

    // ---- QK^T: 16 rows x 32 cols (duplicated across dh siblings) ----
    floatx4 Sc0 = {0.f, 0.f, 0.f, 0.f}, Sc1 = Sc0;
#pragma unroll
    for (int kk = 0; kk < 16; ++kk) {
      int slot = ((kk * 4 + qd) ^ n7) * 8;
      half8 b0 = *(const half8*)&Klds[cur][n][slot];
      half8 b1 = *(const half8*)&Klds[cur][16 + n][slot];
      Sc0 = mfma16(qreg[kk], b0, Sc0);
      Sc1 = mfma16(qreg[kk], b1, Sc1);
    }

    // ---- wave-local online softmax ----
    float alpha[4];
#pragma unroll
    for (int r = 0; r < 4; ++r) {
      float v = fmaxf(Sc0[r], Sc1[r]);
      v = fmaxf(v, __shfl_xor(v, 1, 16));
      v = fmaxf(v, __shfl_xor(v, 2, 16));
      v = fmaxf(v, __shfl_xor(v, 4, 16));
      v = fmaxf(v, __shfl_xor(v, 8, 16));
      float mn = fmaxf(m_st[r], v);
      alpha[r] = __expf(m_st[r] - mn);
      m_st[r] = mn;
    }

    bool unchanged = (alpha[0] == 1.f) & (alpha[1] == 1.f) &
                     (alpha[2] == 1.f) & (alpha[3] == 1.f);
    if (!__all(unchanged)) {
#pragma unroll
      for (int ng = 0; ng < 17; ++ng)
#pragma unroll
        for (int r = 0; r < 4; ++r) O[ng][r] *= alpha[r];
    }

    // ---- P = exp(S-m) -> private scratch (C-layout -> A-layout) ----
#pragma unroll
    for (int r = 0; r < 4; ++r) {
      float p0 = __expf(Sc0[r] - m_st[r]);
      float p1 = __expf(Sc1[r] - m_st[r]);
      Pscr[w][qd * 4 + r][n] = (_Float16)p0;
      Pscr[w][qd * 4 + r][16 + n] = (_Float16)p1;
    }
    half8 av = *(const half8*)&Pscr[w][n][qd * 8];

    // ---- PV: O[16 rows x 256 d (own half)] += P(16x32) @ V(32x256) ----
#pragma unroll
    for (int ng = 0; ng < 16; ++ng) {
      half8 bv = *(const half8*)&Vlds[cur][dh * 256 + ng * 16 + n][qd * 8];
      O[ng] = mfma16(av, bv, O[ng]);
    }
    O[16] = mfma16(av, ones8, O[16]);

    if (st < S_ / 32 - 1) __syncthreads();   // buffer swap (drains prefetch)
  }

  // ---- epilogue: out = O / l (all wave-local) ----
  float* ob = out + ((size_t)b * T_ + t0 + rg * 16) * D_ + dh * 256;
#pragma unroll
  for (int r = 0; r < 4; ++r) {
    float inv = 1.f / O[16][r];
    const size_t rowoff = (size_t)(qd * 4 + r) * D_;
#pragma unroll
    for (int ng = 0; ng < 16; ++ng)
      ob[rowoff + ng * 16 + n] = O[ng][r] * inv;
  }
}

// ---------------------------------------------------------------------------
extern "C" void kernel_launch(void* const* d_in, const int* in_sizes, int n_in,
                              void* d_out, int out_size, void* d_ws, size_t ws_size,
                              hipStream_t stream) {
  (void)in_sizes; (void)n_in; (void)out_size; (void)ws_size;
  const float* main_in = (const float*)d_in[0];   // [B,T,D]
  const float* attn_in = (const float*)d_in[1];   // [B,S,D]
  const float* W_f     = (const float*)d_in[2];   // [D,D]
  const float* b_f     = (const float*)d_in[3];   // [D]
  float* out = (float*)d_out;                     // [B,T,D] fp32

  _Float16* K16 = (_Float16*)d_ws;                        // [B*S, D]
  _Float16* Vt  = K16 + (size_t)B_ * S_ * D_;             // [B, D, S]
  _Float16* X16 = Vt + (size_t)B_ * D_ * S_;              // [B*S, D]
  _Float16* W16 = X16 + (size_t)B_ * S_ * D_;             // [D, D]

  transpose_cast_kernel<<<dim3(D_ / 32, S_ / 32, B_), dim3(32, 8, 1), 0, stream>>>(
      attn_in, Vt, X16);
  wcast_kernel<<<(D_ * D_) / (256 * 4), 256, 0, stream>>>(W_f, W16);
  keys_gemm_kernel<<<dim3((B_ * S_) / 128, D_ / 128), 256, 0, stream>>>(
      X16, W16, b_f, K16);
  flash_kernel<<<(B_ * T_) / 64, 512, 0, stream>>>(main_in, K16, Vt, out);
}